// Round 2
// baseline (1859.588 us; speedup 1.0000x reference)
//
#include <hip/hip_runtime.h>
#include <math.h>

#define BN 4
#define HW 1024
#define SP 1024

static constexpr float EPS = 1e-5f;
static constexpr float TEMPF = 3.0f;
static constexpr float MASK_FILL = 1e-4f;

// ---------------- reductions ----------------
__device__ __forceinline__ float wave_max(float v) {
    for (int o = 32; o; o >>= 1) v = fmaxf(v, __shfl_xor(v, o));
    return v;
}
__device__ __forceinline__ float wave_sum(float v) {
    for (int o = 32; o; o >>= 1) v += __shfl_xor(v, o);
    return v;
}
__device__ __forceinline__ float block_max(float v, float* red) {
    v = wave_max(v);
    int w = threadIdx.x >> 6;
    if ((threadIdx.x & 63) == 0) red[w] = v;
    __syncthreads();
    v = fmaxf(fmaxf(red[0], red[1]), fmaxf(red[2], red[3]));
    __syncthreads();
    return v;
}
__device__ __forceinline__ float block_sum(float v, float* red) {
    v = wave_sum(v);
    int w = threadIdx.x >> 6;
    if ((threadIdx.x & 63) == 0) red[w] = v;
    __syncthreads();
    v = red[0] + red[1] + red[2] + red[3];
    __syncthreads();
    return v;
}

// ---------------- column max over hw for each sp (per batch) ----------------
// grid: 32 blocks, 256 thr. Each block reduces 32 hw-rows.
__global__ void colmax_part(const float* __restrict__ in, float* __restrict__ part) {
    int ch = blockIdx.x;
    const float* base = in + (size_t)ch * 32 * SP;
    float m[4] = {-INFINITY, -INFINITY, -INFINITY, -INFINITY};
    for (int r = 0; r < 32; ++r) {
        const float* row = base + (size_t)r * SP;
#pragma unroll
        for (int k = 0; k < 4; ++k) m[k] = fmaxf(m[k], row[threadIdx.x + k * 256]);
    }
    float* p = part + (size_t)ch * SP;
#pragma unroll
    for (int k = 0; k < 4; ++k) p[threadIdx.x + k * 256] = m[k];
}

// grid: 4 blocks, 256 thr: combine 32 partials, store 1/(max+EPS)
__global__ void colmax_comb(const float* __restrict__ part, float* __restrict__ binv) {
    int col = (blockIdx.x << 8) + threadIdx.x;
    float m = -INFINITY;
    for (int c = 0; c < 32; ++c) m = fmaxf(m, part[(size_t)c * SP + col]);
    binv[col] = 1.0f / (m + EPS);
}

// ---------------- mutual matching (row-max fused), per batch ----------------
// grid: HW blocks (one row of 1024 each)
__global__ void mm_rows(const float* __restrict__ in, const float* __restrict__ binv,
                        float* __restrict__ out) {
    __shared__ float red[4];
    int row = blockIdx.x;
    const float* r = in + (size_t)row * SP;
    float v[4];
#pragma unroll
    for (int k = 0; k < 4; ++k) v[k] = r[threadIdx.x + k * 256];
    float m = fmaxf(fmaxf(v[0], v[1]), fmaxf(v[2], v[3]));
    m = block_max(m, red);
    float rinv = 1.0f / (m + EPS);
    float* o = out + (size_t)row * SP;
#pragma unroll
    for (int k = 0; k < 4; ++k) {
        int sp = threadIdx.x + k * 256;
        o[sp] = v[k] * v[k] * v[k] * rinv * binv[sp];
    }
}

// ---------------- 4D conv layer (per batch) ----------------
// out[co,h,w,hs,ws] = relu( b1[co]+b2[co]
//    + sum_ci,tap in[ci,h+dh,w+dw,hs,ws]*whw[co,ci,tap]
//    + sum_ci,tap in[ci,h,w,hs+dh,ws+dw]*wsp[co,ci,tap] )
// grid: HW blocks (one (h,w) each), 256 thr (4 sp positions each)
template <int CI, int CO, bool ADD>
__global__ __launch_bounds__(256) void conv4d(const float* __restrict__ in,
                                              float* __restrict__ out,
                                              const float* __restrict__ whw,
                                              const float* __restrict__ bhw,
                                              const float* __restrict__ wsp,
                                              const float* __restrict__ bsp) {
    __shared__ float tile[CI * SP];
    __shared__ float wl[2 * CO * CI * 9];
    int hw = blockIdx.x;
    int h = hw >> 5, w = hw & 31;

    for (int i = threadIdx.x; i < CI * 256; i += 256) {
        int ci = i >> 8, p4 = (i & 255) << 2;
        *(float4*)&tile[ci * SP + p4] =
            *(const float4*)&in[((size_t)ci * HW + hw) * SP + p4];
    }
    for (int i = threadIdx.x; i < CO * CI * 9; i += 256) {
        wl[i] = whw[i];
        wl[CO * CI * 9 + i] = wsp[i];
    }
    __syncthreads();

    float acc[CO][4];
#pragma unroll
    for (int co = 0; co < CO; ++co) {
        float bsum = bhw[co] + bsp[co];
#pragma unroll
        for (int k = 0; k < 4; ++k) acc[co][k] = bsum;
    }

    int wsc = threadIdx.x & 31;
    int hs0 = threadIdx.x >> 5;

    for (int ci = 0; ci < CI; ++ci) {
        const float* inc = in + (size_t)ci * HW * SP;
        const float* tl = &tile[ci * SP];
#pragma unroll
        for (int tap = 0; tap < 9; ++tap) {
            int dh = tap / 3 - 1, dw = tap % 3 - 1;
            bool hwok = ((unsigned)(h + dh) < 32u) && ((unsigned)(w + dw) < 32u);
            size_t goff = hwok ? (size_t)(hw + dh * 32 + dw) * SP : 0;  // safe addr
            const float* gp = inc + goff;
            bool wsok = (unsigned)(wsc + dw) < 32u;
            float g[4], l[4];
#pragma unroll
            for (int k = 0; k < 4; ++k) {
                int p = threadIdx.x + k * 256;
                g[k] = hwok ? gp[p] : 0.0f;
                int hs = hs0 + k * 8 + dh;
                l[k] = (wsok && ((unsigned)hs < 32u)) ? tl[p + dh * 32 + dw] : 0.0f;
            }
#pragma unroll
            for (int co = 0; co < CO; ++co) {
                float w1v = wl[(co * CI + ci) * 9 + tap];
                float w2v = wl[CO * CI * 9 + (co * CI + ci) * 9 + tap];
#pragma unroll
                for (int k = 0; k < 4; ++k)
                    acc[co][k] = fmaf(g[k], w1v, fmaf(l[k], w2v, acc[co][k]));
            }
        }
    }

#pragma unroll
    for (int co = 0; co < CO; ++co) {
        float* op = out + ((size_t)co * HW + hw) * SP;
#pragma unroll
        for (int k = 0; k < 4; ++k) {
            int p = threadIdx.x + k * 256;
            float r = fmaxf(acc[co][k], 0.0f);
            if (ADD)
                op[p] += r;
            else
                op[p] = r;
        }
    }
}

// ---------------- mutual matching + mask + softmax (per batch) ----------------
// grid: HW blocks (one q-row each)
__global__ void mm_softmax(const float* __restrict__ s, const float* __restrict__ binv,
                           const int* __restrict__ mask, float* __restrict__ attn) {
    __shared__ float red[4];
    int row = blockIdx.x;
    const float* r = s + (size_t)row * SP;
    float v[4];
#pragma unroll
    for (int k = 0; k < 4; ++k) v[k] = r[threadIdx.x + k * 256];
    float m = fmaxf(fmaxf(v[0], v[1]), fmaxf(v[2], v[3]));
    m = block_max(m, red);
    float rinv = 1.0f / (m + EPS);
    float lg[4];
#pragma unroll
    for (int k = 0; k < 4; ++k) {
        int sp = threadIdx.x + k * 256;
        float val = v[k] * v[k] * v[k] * rinv * binv[sp];
        if (mask[sp] != 0) val = MASK_FILL;
        lg[k] = val * TEMPF;
    }
    float lm = fmaxf(fmaxf(lg[0], lg[1]), fmaxf(lg[2], lg[3]));
    lm = block_max(lm, red);
    float e[4], ss = 0.0f;
#pragma unroll
    for (int k = 0; k < 4; ++k) {
        e[k] = expf(lg[k] - lm);
        ss += e[k];
    }
    ss = block_sum(ss, red);
    float inv = 1.0f / ss;
    float* o = attn + (size_t)row * SP;
#pragma unroll
    for (int k = 0; k < 4; ++k) o[threadIdx.x + k * 256] = e[k] * inv;
}

// ---------------- einsum GEMM: out[c,q] = sum_s V[c,s]*A[q,s] (per batch) ----------------
// grid: (16 qtiles, 4 ctiles), 256 thr, 64x64 tile, 4x4 micro
__global__ __launch_bounds__(256) void gemm_vat(const float* __restrict__ V,
                                                const float* __restrict__ A,
                                                float* __restrict__ out) {
    __shared__ float As[64][36];
    __shared__ float Bs[64][36];
    int c0 = blockIdx.y * 64, q0 = blockIdx.x * 64;
    int tr = threadIdx.x & 15, tc = threadIdx.x >> 4;
    float acc[4][4] = {};
    for (int k0 = 0; k0 < 1024; k0 += 32) {
#pragma unroll
        for (int j = 0; j < 2; ++j) {
            int idx = threadIdx.x + j * 256;
            int row = idx >> 3, c4 = (idx & 7) * 4;
            *(float4*)&As[row][c4] = *(const float4*)&V[(size_t)(c0 + row) * 1024 + k0 + c4];
            *(float4*)&Bs[row][c4] = *(const float4*)&A[(size_t)(q0 + row) * 1024 + k0 + c4];
        }
        __syncthreads();
#pragma unroll
        for (int kk = 0; kk < 8; ++kk) {
            float4 a[4], bb[4];
#pragma unroll
            for (int i = 0; i < 4; ++i) a[i] = *(float4*)&As[tr * 4 + i][kk * 4];
#pragma unroll
            for (int j = 0; j < 4; ++j) bb[j] = *(float4*)&Bs[tc * 4 + j][kk * 4];
#pragma unroll
            for (int i = 0; i < 4; ++i)
#pragma unroll
                for (int j = 0; j < 4; ++j)
                    acc[i][j] += a[i].x * bb[j].x + a[i].y * bb[j].y +
                                 a[i].z * bb[j].z + a[i].w * bb[j].w;
        }
        __syncthreads();
    }
#pragma unroll
    for (int i = 0; i < 4; ++i) {
        float4 o = {acc[i][0], acc[i][1], acc[i][2], acc[i][3]};
        *(float4*)&out[(size_t)(c0 + tr * 4 + i) * 1024 + q0 + tc * 4] = o;
    }
}

extern "C" void kernel_launch(void* const* d_in, const int* in_sizes, int n_in,
                              void* d_out, int out_size, void* d_ws, size_t ws_size,
                              hipStream_t stream) {
    const float* corr = (const float*)d_in[0];
    const float* v = (const float*)d_in[1];
    const int* mask = (const int*)d_in[2];
    const float* l0w1 = (const float*)d_in[3];
    const float* l0b1 = (const float*)d_in[4];
    const float* l0w2 = (const float*)d_in[5];
    const float* l0b2 = (const float*)d_in[6];
    const float* l1w1 = (const float*)d_in[7];
    const float* l1b1 = (const float*)d_in[8];
    const float* l1w2 = (const float*)d_in[9];
    const float* l1b2 = (const float*)d_in[10];
    const float* l2w1 = (const float*)d_in[11];
    const float* l2b1 = (const float*)d_in[12];
    const float* l2w2 = (const float*)d_in[13];
    const float* l2b2 = (const float*)d_in[14];

    // per-batch workspace: P,Q (10ch) + C1,S (1ch) + reductions  ~92.4 MB
    float* W = (float*)d_ws;
    const size_t CH10 = (size_t)10 * HW * SP;  // 10,485,760 floats
    const size_t CH1 = (size_t)HW * SP;        // 1,048,576 floats
    float* P = W;
    float* Q = P + CH10;
    float* C1 = Q + CH10;
    float* S = C1 + CH1;
    float* PART = S + CH1;
    float* MB0 = PART + 32 * SP;
    float* MB1 = MB0 + SP;
    float* ATTN = C1;  // C1 dead after branch-2 layer 0 of this batch
    float* out = (float*)d_out;
    (void)in_sizes; (void)n_in; (void)out_size; (void)ws_size;

    for (int b = 0; b < BN; ++b) {
        const float* corr_b = corr + (size_t)b * HW * SP;
        const float* v_b = v + (size_t)b * 256 * SP;
        const int* mask_b = mask + (size_t)b * SP;
        float* out_b = out + (size_t)b * 256 * SP;

        // first mutual matching
        colmax_part<<<32, 256, 0, stream>>>(corr_b, PART);
        colmax_comb<<<4, 256, 0, stream>>>(PART, MB0);
        mm_rows<<<HW, 256, 0, stream>>>(corr_b, MB0, C1);

        // branch 1: (h,w)-conv uses w1, (hs,ws)-conv uses w2
        conv4d<1, 10, false><<<HW, 256, 0, stream>>>(C1, P, l0w1, l0b1, l0w2, l0b2);
        conv4d<10, 10, false><<<HW, 256, 0, stream>>>(P, Q, l1w1, l1b1, l1w2, l1b2);
        conv4d<10, 1, false><<<HW, 256, 0, stream>>>(Q, S, l2w1, l2b1, l2w2, l2b2);

        // branch 2 (transposed orientation == swap w1/w2 roles)
        conv4d<1, 10, false><<<HW, 256, 0, stream>>>(C1, P, l0w2, l0b2, l0w1, l0b1);
        conv4d<10, 10, false><<<HW, 256, 0, stream>>>(P, Q, l1w2, l1b2, l1w1, l1b1);
        conv4d<10, 1, true><<<HW, 256, 0, stream>>>(Q, S, l2w2, l2b2, l2w1, l2b1);

        // second mutual matching + mask + softmax
        colmax_part<<<32, 256, 0, stream>>>(S, PART);
        colmax_comb<<<4, 256, 0, stream>>>(PART, MB1);
        mm_softmax<<<HW, 256, 0, stream>>>(S, MB1, mask_b, ATTN);

        // weighted_v = einsum('cs,qs->cq') for this batch
        dim3 ggrid(16, 4);
        gemm_vat<<<ggrid, 256, 0, stream>>>(v_b, ATTN, out_b);
    }
}